// Round 2
// baseline (173.874 us; speedup 1.0000x reference)
//
#include <hip/hip_runtime.h>

#define OUT_DIM 128

// --- kernel 1: zero maxd, project nodes through W_theta -> p[i], compute mean(W_phi)
__global__ void init_kernel(float* __restrict__ maxd, float* __restrict__ p,
                            float* __restrict__ meanW,
                            const float* __restrict__ nodes,
                            const float* __restrict__ Wt,
                            const float* __restrict__ W_phi, int n) {
    int i = blockIdx.x * blockDim.x + threadIdx.x;
    if (i < n) {
        maxd[i] = 0.0f;
        float x = nodes[3 * i + 0], y = nodes[3 * i + 1], z = nodes[3 * i + 2];
        p[i] = x * Wt[0] + y * Wt[1] + z * Wt[2];
    }
    if (blockIdx.x == 0 && threadIdx.x == 0) {
        float s = 0.0f;
        #pragma unroll
        for (int j = 0; j < OUT_DIM; ++j) s += W_phi[j];
        *meanW = s / (float)OUT_DIM;
    }
}

// --- kernel 2: 4 edges/thread; d = |p[r]-p[c]|; guarded atomic max
__global__ void edge_kernel(const float* __restrict__ p,
                            const int* __restrict__ row,
                            const int* __restrict__ col,
                            float* __restrict__ maxd, int E) {
    int t = blockIdx.x * blockDim.x + threadIdx.x;
    int base = t * 4;
    if (base >= E) return;

    if (base + 3 < E) {
        int4 r = *(const int4*)(row + base);
        int4 c = *(const int4*)(col + base);
        // issue all scattered loads up front for MLP
        float pr0 = p[r.x], pc0 = p[c.x];
        float pr1 = p[r.y], pc1 = p[c.y];
        float pr2 = p[r.z], pc2 = p[c.z];
        float pr3 = p[r.w], pc3 = p[c.w];
        float d0 = fabsf(pr0 - pc0);
        float d1 = fabsf(pr1 - pc1);
        float d2 = fabsf(pr2 - pc2);
        float d3 = fabsf(pr3 - pc3);
        // maxd >= 0 always, so int-bit compare == float compare.
        // Guard read: maxd only grows; stale read => extra atomic, never a miss.
        if (d0 > maxd[r.x]) atomicMax((int*)&maxd[r.x], __float_as_int(d0));
        if (d1 > maxd[r.y]) atomicMax((int*)&maxd[r.y], __float_as_int(d1));
        if (d2 > maxd[r.z]) atomicMax((int*)&maxd[r.z], __float_as_int(d2));
        if (d3 > maxd[r.w]) atomicMax((int*)&maxd[r.w], __float_as_int(d3));
    } else {
        for (int e = base; e < E; ++e) {
            int r = row[e], c = col[e];
            float d = fabsf(p[r] - p[c]);
            if (d > maxd[r]) atomicMax((int*)&maxd[r], __float_as_int(d));
        }
    }
}

// --- kernel 3: final combine (vectorized)
__global__ void final_kernel(const float* __restrict__ prev,
                             const float* __restrict__ maxd,
                             const float* __restrict__ meanW,
                             float* __restrict__ out, int n) {
    int i = blockIdx.x * blockDim.x + threadIdx.x;
    int base = i * 4;
    if (base >= n) return;
    float mw = *meanW;
    if (base + 3 < n) {
        float4 pv = *(const float4*)(prev + base);
        float4 mv = *(const float4*)(maxd + base);
        float4 o;
        o.x = 0.5f * (pv.x + mw * mv.x);
        o.y = 0.5f * (pv.y + mw * mv.y);
        o.z = 0.5f * (pv.z + mw * mv.z);
        o.w = 0.5f * (pv.w + mw * mv.w);
        *(float4*)(out + base) = o;
    } else {
        for (int j = base; j < n; ++j)
            out[j] = 0.5f * (prev[j] + mw * maxd[j]);
    }
}

extern "C" void kernel_launch(void* const* d_in, const int* in_sizes, int n_in,
                              void* d_out, int out_size, void* d_ws, size_t ws_size,
                              hipStream_t stream) {
    const float* prev    = (const float*)d_in[0];   // [N]
    const float* nodes   = (const float*)d_in[1];   // [N,3]
    const int*   row     = (const int*)d_in[2];     // [E]
    const int*   col     = (const int*)d_in[3];     // [E]
    const float* W_phi   = (const float*)d_in[4];   // [128]
    const float* W_theta = (const float*)d_in[5];   // [3]

    const int N = in_sizes[0];
    const int E = in_sizes[2];

    float* maxd  = (float*)d_ws;              // N floats
    float* p     = (float*)d_ws + N;          // N floats
    float* meanW = (float*)d_ws + 2 * N;      // 1 float

    float* out = (float*)d_out;

    const int B = 256;
    init_kernel<<<(N + B - 1) / B, B, 0, stream>>>(maxd, p, meanW, nodes, W_theta, W_phi, N);
    int tE = (E + 3) / 4;
    edge_kernel<<<(tE + B - 1) / B, B, 0, stream>>>(p, row, col, maxd, E);
    int tN = (N + 3) / 4;
    final_kernel<<<(tN + B - 1) / B, B, 0, stream>>>(prev, maxd, meanW, out, N);
}